// Round 1
// baseline (215.703 us; speedup 1.0000x reference)
//
#include <hip/hip_runtime.h>
#include <cstdint>

#define DEV __device__ __forceinline__

typedef __attribute__((ext_vector_type(4))) float f32x4;
typedef __attribute__((ext_vector_type(8))) short short8;
typedef __attribute__((ext_vector_type(4))) unsigned short u16x4;

constexpr int BS  = 4;
constexpr int SEQ = 2048;
constexpr int DIM = 1024;

DEV ushort f2b(float f){
  uint32_t u = __builtin_bit_cast(uint32_t, f);
  u += 0x7fffu + ((u >> 16) & 1u);
  return (ushort)(u >> 16);
}

DEV void gload_lds16(const void* g, void* l){
  __builtin_amdgcn_global_load_lds(
      (const __attribute__((address_space(1))) unsigned int*)g,
      (__attribute__((address_space(3))) unsigned int*)l, 16, 0, 0);
}

// ---------- fp32 -> bf16 convert, 8 elems/thread ----------
__global__ __launch_bounds__(256) void convert_f2b8(const float* __restrict__ src,
                                                    ushort* __restrict__ dst){
  long i = (long)blockIdx.x * 256 + threadIdx.x;
  const f32x4* s4 = (const f32x4*)src;
  f32x4 a = s4[i*2], b = s4[i*2+1];
  short8 o;
  o[0]=(short)f2b(a[0]); o[1]=(short)f2b(a[1]); o[2]=(short)f2b(a[2]); o[3]=(short)f2b(a[3]);
  o[4]=(short)f2b(b[0]); o[5]=(short)f2b(b[1]); o[6]=(short)f2b(b[2]); o[7]=(short)f2b(b[3]);
  ((short8*)dst)[i] = o;
}

// ---------- transpose fp32 [R][C] -> bf16 [C][R] ----------
__global__ __launch_bounds__(256) void transpose_f2b(const float* __restrict__ src,
                                                     ushort* __restrict__ dst,
                                                     int R, int C){
  __shared__ float t[32][33];
  int c0 = blockIdx.x * 32, r0 = blockIdx.y * 32;
  int tx = threadIdx.x, ty = threadIdx.y;
  #pragma unroll
  for (int k=0;k<4;k++) t[ty+k*8][tx] = src[(long)(r0+ty+k*8)*C + c0+tx];
  __syncthreads();
  #pragma unroll
  for (int k=0;k<4;k++) dst[(long)(c0+ty+k*8)*R + r0+tx] = f2b(t[tx][ty+k*8]);
}

// ---------- transpose bf16 [R][C] -> bf16 [C][R] ----------
__global__ __launch_bounds__(256) void transpose_b2b(const ushort* __restrict__ src,
                                                     ushort* __restrict__ dst,
                                                     int R, int C){
  __shared__ ushort t[32][33];
  int c0 = blockIdx.x * 32, r0 = blockIdx.y * 32;
  int tx = threadIdx.x, ty = threadIdx.y;
  #pragma unroll
  for (int k=0;k<4;k++) t[ty+k*8][tx] = src[(long)(r0+ty+k*8)*C + c0+tx];
  __syncthreads();
  #pragma unroll
  for (int k=0;k<4;k++) dst[(long)(c0+ty+k*8)*R + r0+tx] = t[tx][ty+k*8];
}

// ---------- generic 128x128 bf16 GEMM, B pre-transposed ("bt") ----------
// C[m][n] = sum_k A[m][k] * Bt[n][k]   (+ optional bias[n])
struct GArgs {
  const ushort* A;  long lda; long aBS;
  const ushort* Bm; long ldb; long bBS;
  void* C;          long ldc; long cBS;
  const float* bias;
  int K;
  int causal;   // 0 none; 1 skip fully-masked tiles (scores); 2 K limited to m0+128 (PV)
};

template<bool OUT_BF16, bool HAS_BIAS>
__global__ __launch_bounds__(256,2) void gemm_bt(GArgs g){
  __shared__ ushort aL[128*32];
  __shared__ ushort bL[128*32];
  int m0 = blockIdx.x * 128, n0 = blockIdx.y * 128;
  int z  = blockIdx.z;
  if (g.causal == 1 && n0 > m0) return;           // fully masked score tile
  int Keff = (g.causal == 2) ? ((g.K < m0+128) ? g.K : m0+128) : g.K;
  const char* Ab = (const char*)(g.A  + (long)z * g.aBS);
  const char* Bb = (const char*)(g.Bm + (long)z * g.bBS);
  int tid = threadIdx.x;
  int wid = tid >> 6, lane = tid & 63;
  int wr = wid >> 1, wc = wid & 1;
  int lr = lane & 15, lk = lane >> 4;
  f32x4 acc[4][4];
  #pragma unroll
  for (int m=0;m<4;m++)
    #pragma unroll
    for (int n=0;n<4;n++) acc[m][n] = f32x4{0.f,0.f,0.f,0.f};

  for (int k0 = 0; k0 < Keff; k0 += 32){
    __syncthreads();                              // prior frag reads done
    #pragma unroll
    for (int rd=0; rd<2; rd++){
      int ob = (rd*4 + wid) * 1024;               // wave-uniform byte base in tile
      int o  = ob + (lane << 4);                  // this lane's byte offset
      int r  = o >> 6, cb = o & 63;               // tile row (64B rows), byte-in-row
      gload_lds16(Ab + ((long)(m0+r)*g.lda + k0)*2 + cb, (char*)aL + ob);
      gload_lds16(Bb + ((long)(n0+r)*g.ldb + k0)*2 + cb, (char*)bL + ob);
    }
    __syncthreads();                              // vmcnt(0) drain -> staged data ready
    short8 af[4], bf4[4];
    #pragma unroll
    for (int m=0;m<4;m++) af[m]  = *(const short8*)&aL[(wr*64 + m*16 + lr)*32 + lk*8];
    #pragma unroll
    for (int n=0;n<4;n++) bf4[n] = *(const short8*)&bL[(wc*64 + n*16 + lr)*32 + lk*8];
    #pragma unroll
    for (int m=0;m<4;m++)
      #pragma unroll
      for (int n=0;n<4;n++)
        acc[m][n] = __builtin_amdgcn_mfma_f32_16x16x32_bf16(af[m], bf4[n], acc[m][n], 0, 0, 0);
  }

  long cz = (long)z * g.cBS;
  #pragma unroll
  for (int m=0;m<4;m++){
    int row0 = m0 + wr*64 + m*16 + lk*4;
    #pragma unroll
    for (int n=0;n<4;n++){
      int col = n0 + wc*64 + n*16 + lr;
      float bv = HAS_BIAS ? g.bias[col] : 0.0f;
      #pragma unroll
      for (int i=0;i<4;i++){
        float v = acc[m][n][i] + bv;
        long off = cz + (long)(row0+i)*g.ldc + col;
        if (OUT_BF16) ((ushort*)g.C)[off] = f2b(v);
        else          ((float*)g.C)[off]  = v;
      }
    }
  }
}

// ---------- causal row softmax: P = softmax(scores * 1/32) ----------
__global__ __launch_bounds__(256) void softmax_causal(const float* __restrict__ sc,
                                                      ushort* __restrict__ P){
  int row = blockIdx.x & (SEQ-1);
  int b   = blockIdx.x >> 11;
  const f32x4* srow = (const f32x4*)(sc + ((long)b*SEQ + row)*(long)SEQ);
  ushort* prow = P + ((long)b*SEQ + row)*(long)SEQ;
  int tid = threadIdx.x;
  int lane = tid & 63, wid = tid >> 6;
  const float scale = 0.03125f;
  float x[8]; float mx = -INFINITY;
  #pragma unroll
  for (int k=0;k<2;k++){
    f32x4 v = srow[k*256 + tid];
    #pragma unroll
    for (int j=0;j<4;j++){
      int idx = k*1024 + tid*4 + j;
      float t = (idx <= row) ? v[j] : -INFINITY;
      x[k*4+j] = t; mx = fmaxf(mx, t);
    }
  }
  #pragma unroll
  for (int off=1; off<64; off<<=1) mx = fmaxf(mx, __shfl_xor(mx, off));
  __shared__ float rb[8];
  if (lane == 0) rb[wid] = mx;
  __syncthreads();
  mx = fmaxf(fmaxf(rb[0],rb[1]), fmaxf(rb[2],rb[3]));
  float sum = 0.f; float e[8];
  #pragma unroll
  for (int i=0;i<8;i++){ e[i] = __expf((x[i]-mx)*scale); sum += e[i]; }
  #pragma unroll
  for (int off=1; off<64; off<<=1) sum += __shfl_xor(sum, off);
  if (lane == 0) rb[4+wid] = sum;
  __syncthreads();
  sum = (rb[4]+rb[5]) + (rb[6]+rb[7]);
  float inv = 1.0f / sum;
  #pragma unroll
  for (int k=0;k<2;k++){
    u16x4 o;
    #pragma unroll
    for (int j=0;j<4;j++) o[j] = f2b(e[k*4+j]*inv);
    ((u16x4*)prow)[k*256 + tid] = o;
  }
}

extern "C" void kernel_launch(void* const* d_in, const int* in_sizes, int n_in,
                              void* d_out, int out_size, void* d_ws, size_t ws_size,
                              hipStream_t stream){
  const float* x  = (const float*)d_in[0];
  const float* Wq = (const float*)d_in[1];
  const float* Wk = (const float*)d_in[2];
  const float* Wv = (const float*)d_in[3];
  const float* bq = (const float*)d_in[4];
  const float* bk = (const float*)d_in[5];
  const float* bv = (const float*)d_in[6];
  float* out = (float*)d_out;

  // workspace layout (bytes)
  const long XB = 0;            // x bf16            [8192][1024]  16 MB
  const long WT = 16777216;     // Wt bf16 x3        [3][1024][1024] 6 MB
  const long QB = 23068672;     // q bf16            16 MB
  const long KB = 39845888;     // k bf16            16 MB
  const long VB = 56623104;     // v bf16            16 MB
  const long VT = 73400320;     // v^T bf16 [1024][8192] 16 MB
  const long SC = 90177536;     // scores fp32 [4][2048][2048] 64 MB
  const long NEED = 157286400;
  const long PB = 0;            // P bf16 [4][2048][2048] 32 MB, overlays dead xb/wt/qb-front
  if ((long)ws_size < NEED) return;   // cannot run without scratch

  char* ws = (char*)d_ws;
  ushort* xb = (ushort*)(ws + XB);
  ushort* wt = (ushort*)(ws + WT);
  ushort* qb = (ushort*)(ws + QB);
  ushort* kb = (ushort*)(ws + KB);
  ushort* vb = (ushort*)(ws + VB);
  ushort* vt = (ushort*)(ws + VT);
  float*  sc = (float* )(ws + SC);
  ushort* pb = (ushort*)(ws + PB);

  dim3 tb(32, 8);

  convert_f2b8<<<4096, 256, 0, stream>>>(x, xb);
  transpose_f2b<<<dim3(32,32), tb, 0, stream>>>(Wq, wt + 0,       1024, 1024);
  transpose_f2b<<<dim3(32,32), tb, 0, stream>>>(Wk, wt + 1048576, 1024, 1024);
  transpose_f2b<<<dim3(32,32), tb, 0, stream>>>(Wv, wt + 2097152, 1024, 1024);

  // projections: q/k/v = x @ W + b
  GArgs pa{};
  pa.A = xb; pa.lda = 1024; pa.aBS = 0;
  pa.ldb = 1024; pa.bBS = 0;
  pa.ldc = 1024; pa.cBS = 0;
  pa.K = 1024; pa.causal = 0;
  pa.Bm = wt;           pa.C = (void*)qb; pa.bias = bq;
  gemm_bt<true,true><<<dim3(64,8,1), 256, 0, stream>>>(pa);
  pa.Bm = wt + 1048576; pa.C = (void*)kb; pa.bias = bk;
  gemm_bt<true,true><<<dim3(64,8,1), 256, 0, stream>>>(pa);
  pa.Bm = wt + 2097152; pa.C = (void*)vb; pa.bias = bv;
  gemm_bt<true,true><<<dim3(64,8,1), 256, 0, stream>>>(pa);

  transpose_b2b<<<dim3(32,256), tb, 0, stream>>>(vb, vt, 8192, 1024);

  // scores = q @ k^T per batch (skip fully-masked tiles)
  GArgs sa{};
  sa.A = qb;  sa.lda = 1024; sa.aBS = (long)SEQ*1024;
  sa.Bm = kb; sa.ldb = 1024; sa.bBS = (long)SEQ*1024;
  sa.C = (void*)sc; sa.ldc = SEQ; sa.cBS = (long)SEQ*SEQ;
  sa.bias = nullptr; sa.K = 1024; sa.causal = 1;
  gemm_bt<false,false><<<dim3(16,16,4), 256, 0, stream>>>(sa);

  softmax_causal<<<BS*SEQ, 256, 0, stream>>>(sc, pb);

  // out = P @ V  (B-operand = V^T rows, per-batch column offset; causal K-limit)
  GArgs va{};
  va.A = pb;  va.lda = SEQ;  va.aBS = (long)SEQ*SEQ;
  va.Bm = vt; va.ldb = 8192; va.bBS = SEQ;
  va.C = (void*)out; va.ldc = 1024; va.cBS = (long)SEQ*1024;
  va.bias = nullptr; va.K = SEQ; va.causal = 2;
  gemm_bt<false,false><<<dim3(16,8,4), 256, 0, stream>>>(va);
}

// Round 2
// 214.367 us; speedup vs baseline: 1.0062x; 1.0062x over previous
//
#include <hip/hip_runtime.h>
#include <cstdint>

#define DEV __device__ __forceinline__

typedef __attribute__((ext_vector_type(4))) float f32x4;
typedef __attribute__((ext_vector_type(8))) short short8;
typedef __attribute__((ext_vector_type(4))) unsigned short u16x4;

constexpr int BS  = 4;
constexpr int SEQ = 2048;
constexpr int DIM = 1024;

DEV ushort f2b(float f){
  uint32_t u = __builtin_bit_cast(uint32_t, f);
  u += 0x7fffu + ((u >> 16) & 1u);
  return (ushort)(u >> 16);
}

DEV void gload_lds16(const void* g, void* l){
  __builtin_amdgcn_global_load_lds(
      (const __attribute__((address_space(1))) unsigned int*)g,
      (__attribute__((address_space(3))) unsigned int*)l, 16, 0, 0);
}

// ---------- fp32 -> bf16 convert, 8 elems/thread ----------
__global__ __launch_bounds__(256) void convert_f2b8(const float* __restrict__ src,
                                                    ushort* __restrict__ dst){
  long i = (long)blockIdx.x * 256 + threadIdx.x;
  const f32x4* s4 = (const f32x4*)src;
  f32x4 a = s4[i*2], b = s4[i*2+1];
  short8 o;
  o[0]=(short)f2b(a[0]); o[1]=(short)f2b(a[1]); o[2]=(short)f2b(a[2]); o[3]=(short)f2b(a[3]);
  o[4]=(short)f2b(b[0]); o[5]=(short)f2b(b[1]); o[6]=(short)f2b(b[2]); o[7]=(short)f2b(b[3]);
  ((short8*)dst)[i] = o;
}

// ---------- transpose fp32 [R][C] -> bf16 [C][R] ----------
__global__ __launch_bounds__(256) void transpose_f2b(const float* __restrict__ src,
                                                     ushort* __restrict__ dst,
                                                     int R, int C){
  __shared__ float t[32][33];
  int c0 = blockIdx.x * 32, r0 = blockIdx.y * 32;
  int tx = threadIdx.x, ty = threadIdx.y;
  #pragma unroll
  for (int k=0;k<4;k++) t[ty+k*8][tx] = src[(long)(r0+ty+k*8)*C + c0+tx];
  __syncthreads();
  #pragma unroll
  for (int k=0;k<4;k++) dst[(long)(c0+ty+k*8)*R + r0+tx] = f2b(t[tx][ty+k*8]);
}

// ---------- transpose bf16 [R][C] -> bf16 [C][R] ----------
__global__ __launch_bounds__(256) void transpose_b2b(const ushort* __restrict__ src,
                                                     ushort* __restrict__ dst,
                                                     int R, int C){
  __shared__ ushort t[32][33];
  int c0 = blockIdx.x * 32, r0 = blockIdx.y * 32;
  int tx = threadIdx.x, ty = threadIdx.y;
  #pragma unroll
  for (int k=0;k<4;k++) t[ty+k*8][tx] = src[(long)(r0+ty+k*8)*C + c0+tx];
  __syncthreads();
  #pragma unroll
  for (int k=0;k<4;k++) dst[(long)(c0+ty+k*8)*R + r0+tx] = t[tx][ty+k*8];
}

// ---------- 128x128 bf16 GEMM, B pre-transposed, 2-phase double-buffered ----------
// C[m][n] = sum_k A[m][k] * Bt[n][k]
// MODE 0: fused QKV (bf16 out to q/k/v by n0>>10, bias b0/b1/b2)
// MODE 1: scores (fp32 out, skip tiles n0>m0)
// MODE 2: PV (fp32 out, K limited to m0+128)
struct GArgs {
  const ushort* A;  long lda; long aBS;
  const ushort* Bm; long ldb; long bBS;
  void* C;          long ldc; long cBS;
  const float* b0; const float* b1; const float* b2;
  int K;
};

template<int MODE>
__global__ __launch_bounds__(256) void gemm2(GArgs g){
  __shared__ ushort aL[2][128*32];
  __shared__ ushort bL[2][128*32];
  int m0 = blockIdx.x * 128, n0 = blockIdx.y * 128;
  int z  = blockIdx.z;
  if (MODE == 1 && n0 > m0) return;               // fully masked score tile
  int Keff = (MODE == 2) ? ((g.K < m0+128) ? g.K : m0+128) : g.K;
  const char* Ab = (const char*)(g.A  + (long)z * g.aBS);
  const char* Bb = (const char*)(g.Bm + (long)z * g.bBS);
  int tid = threadIdx.x;
  int wid = tid >> 6, lane = tid & 63;
  int wr = wid >> 1, wc = wid & 1;
  int lr = lane & 15, lk = lane >> 4;

  // per-thread staging geometry (identical to verified round-1 layout)
  int ob0 = (0*4 + wid) * 1024;                   // wave-uniform byte base, chunk 0
  int ob1 = (1*4 + wid) * 1024;                   // chunk 1
  int o0  = ob0 + (lane << 4);
  int o1  = ob1 + (lane << 4);
  int r0_ = o0 >> 6, cb0 = o0 & 63;
  int r1_ = o1 >> 6, cb1 = o1 & 63;

  auto stage = [&](int buf, int k0){
    gload_lds16(Ab + ((long)(m0+r0_)*g.lda + k0)*2 + cb0, (char*)aL[buf] + ob0);
    gload_lds16(Bb + ((long)(n0+r0_)*g.ldb + k0)*2 + cb0, (char*)bL[buf] + ob0);
    gload_lds16(Ab + ((long)(m0+r1_)*g.lda + k0)*2 + cb1, (char*)aL[buf] + ob1);
    gload_lds16(Bb + ((long)(n0+r1_)*g.ldb + k0)*2 + cb1, (char*)bL[buf] + ob1);
  };

  f32x4 acc[4][4];
  #pragma unroll
  for (int m=0;m<4;m++)
    #pragma unroll
    for (int n=0;n<4;n++) acc[m][n] = f32x4{0.f,0.f,0.f,0.f};

  int nt = Keff >> 5;                             // K multiple of 32 always here
  stage(0, 0);
  __syncthreads();                                // vmcnt(0)+lgkmcnt(0)+barrier
  int cur = 0;
  for (int t = 0; t < nt-1; ++t){
    stage(cur ^ 1, (t+1) << 5);                   // next-tile loads in flight
    short8 af[4], bf4[4];
    #pragma unroll
    for (int m=0;m<4;m++) af[m]  = *(const short8*)&aL[cur][(wr*64 + m*16 + lr)*32 + lk*8];
    #pragma unroll
    for (int n=0;n<4;n++) bf4[n] = *(const short8*)&bL[cur][(wc*64 + n*16 + lr)*32 + lk*8];
    #pragma unroll
    for (int m=0;m<4;m++)
      #pragma unroll
      for (int n=0;n<4;n++)
        acc[m][n] = __builtin_amdgcn_mfma_f32_16x16x32_bf16(af[m], bf4[n], acc[m][n], 0, 0, 0);
    __syncthreads();                              // drains stage loads + frag reads
    cur ^= 1;
  }
  { // last K-tile, no prefetch
    short8 af[4], bf4[4];
    #pragma unroll
    for (int m=0;m<4;m++) af[m]  = *(const short8*)&aL[cur][(wr*64 + m*16 + lr)*32 + lk*8];
    #pragma unroll
    for (int n=0;n<4;n++) bf4[n] = *(const short8*)&bL[cur][(wc*64 + n*16 + lr)*32 + lk*8];
    #pragma unroll
    for (int m=0;m<4;m++)
      #pragma unroll
      for (int n=0;n<4;n++)
        acc[m][n] = __builtin_amdgcn_mfma_f32_16x16x32_bf16(af[m], bf4[n], acc[m][n], 0, 0, 0);
  }

  if (MODE == 0){
    int sel = n0 >> 10;                           // tile lies in one of q/k/v
    const float* bp = (sel == 0) ? g.b0 : (sel == 1) ? g.b1 : g.b2;
    long cbase = (long)sel * 8388608;             // 8192*1024 elements apart
    #pragma unroll
    for (int m=0;m<4;m++){
      int row0 = m0 + wr*64 + m*16 + lk*4;
      #pragma unroll
      for (int n=0;n<4;n++){
        int col  = n0 + wc*64 + n*16 + lr;
        int colq = col & 1023;
        float bv = bp[colq];
        #pragma unroll
        for (int i=0;i<4;i++)
          ((ushort*)g.C)[cbase + (long)(row0+i)*1024 + colq] = f2b(acc[m][n][i] + bv);
      }
    }
  } else {
    long cz = (long)z * g.cBS;
    #pragma unroll
    for (int m=0;m<4;m++){
      int row0 = m0 + wr*64 + m*16 + lk*4;
      #pragma unroll
      for (int n=0;n<4;n++){
        int col = n0 + wc*64 + n*16 + lr;
        #pragma unroll
        for (int i=0;i<4;i++)
          ((float*)g.C)[cz + (long)(row0+i)*g.ldc + col] = acc[m][n][i];
      }
    }
  }
}

// ---------- causal row softmax: P = softmax(scores * 1/32), prefix-trimmed ----------
__global__ __launch_bounds__(256) void softmax_causal(const float* __restrict__ sc,
                                                      ushort* __restrict__ P){
  int row = blockIdx.x & (SEQ-1);
  int b   = blockIdx.x >> 11;
  const f32x4* srow = (const f32x4*)(sc + ((long)b*SEQ + row)*(long)SEQ);
  ushort* prow = P + ((long)b*SEQ + row)*(long)SEQ;
  int tid = threadIdx.x;
  int lane = tid & 63, wid = tid >> 6;
  const float scale = 0.03125f;
  float x[8]; float mx = -INFINITY;
  #pragma unroll
  for (int k=0;k<2;k++){
    int base = k*1024 + tid*4;
    if (base <= row){
      f32x4 v = srow[k*256 + tid];
      #pragma unroll
      for (int j=0;j<4;j++){
        float t = (base + j <= row) ? v[j] : -INFINITY;
        x[k*4+j] = t; mx = fmaxf(mx, t);
      }
    } else {
      #pragma unroll
      for (int j=0;j<4;j++) x[k*4+j] = -INFINITY;
    }
  }
  #pragma unroll
  for (int off=1; off<64; off<<=1) mx = fmaxf(mx, __shfl_xor(mx, off));
  __shared__ float rb[8];
  if (lane == 0) rb[wid] = mx;
  __syncthreads();
  mx = fmaxf(fmaxf(rb[0],rb[1]), fmaxf(rb[2],rb[3]));
  float sum = 0.f; float e[8];
  #pragma unroll
  for (int i=0;i<8;i++){ e[i] = __expf((x[i]-mx)*scale); sum += e[i]; }
  #pragma unroll
  for (int off=1; off<64; off<<=1) sum += __shfl_xor(sum, off);
  if (lane == 0) rb[4+wid] = sum;
  __syncthreads();
  sum = (rb[4]+rb[5]) + (rb[6]+rb[7]);
  float inv = 1.0f / sum;
  int wlim = row | 127;                           // PV reads cols <= m0+127 = row|127
  #pragma unroll
  for (int k=0;k<2;k++){
    int base = k*1024 + tid*4;
    if (base <= wlim){
      u16x4 o;
      #pragma unroll
      for (int j=0;j<4;j++) o[j] = f2b(e[k*4+j]*inv);
      ((u16x4*)prow)[k*256 + tid] = o;
    }
  }
}

extern "C" void kernel_launch(void* const* d_in, const int* in_sizes, int n_in,
                              void* d_out, int out_size, void* d_ws, size_t ws_size,
                              hipStream_t stream){
  const float* x  = (const float*)d_in[0];
  const float* Wq = (const float*)d_in[1];
  const float* Wk = (const float*)d_in[2];
  const float* Wv = (const float*)d_in[3];
  const float* bq = (const float*)d_in[4];
  const float* bk = (const float*)d_in[5];
  const float* bv = (const float*)d_in[6];
  float* out = (float*)d_out;

  // workspace layout (bytes)
  const long XB = 0;            // x bf16            [8192][1024]  16 MB
  const long WT = 16777216;     // Wt bf16 x3        [3][1024][1024] 6 MB
  const long QB = 23068672;     // q/k/v bf16 contiguous  48 MB
  const long VT = 73400320;     // v^T bf16 [1024][8192] 16 MB
  const long SC = 90177536;     // scores fp32 [4][2048][2048] 64 MB
  const long NEED = 157286400;
  const long PB = 0;            // P bf16, overlays dead xb/wt/q-front
  if ((long)ws_size < NEED) return;

  char* ws = (char*)d_ws;
  ushort* xb = (ushort*)(ws + XB);
  ushort* wt = (ushort*)(ws + WT);
  ushort* qb = (ushort*)(ws + QB);
  ushort* kb = qb + 8388608;
  ushort* vb = qb + 16777216;
  ushort* vt = (ushort*)(ws + VT);
  float*  sc = (float* )(ws + SC);
  ushort* pb = (ushort*)(ws + PB);

  dim3 tb(32, 8);

  convert_f2b8<<<4096, 256, 0, stream>>>(x, xb);
  transpose_f2b<<<dim3(32,32), tb, 0, stream>>>(Wq, wt + 0,       1024, 1024);
  transpose_f2b<<<dim3(32,32), tb, 0, stream>>>(Wk, wt + 1048576, 1024, 1024);
  transpose_f2b<<<dim3(32,32), tb, 0, stream>>>(Wv, wt + 2097152, 1024, 1024);

  // fused projections: [q|k|v] = x @ [Wq|Wk|Wv] + [bq|bk|bv], N=3072
  GArgs pa{};
  pa.A = xb; pa.lda = 1024; pa.aBS = 0;
  pa.Bm = wt; pa.ldb = 1024; pa.bBS = 0;
  pa.C = (void*)qb; pa.ldc = 1024; pa.cBS = 0;
  pa.b0 = bq; pa.b1 = bk; pa.b2 = bv;
  pa.K = 1024;
  gemm2<0><<<dim3(64,24,1), 256, 0, stream>>>(pa);

  transpose_b2b<<<dim3(32,256), tb, 0, stream>>>(vb, vt, 8192, 1024);

  // scores = q @ k^T per batch (skip fully-masked tiles)
  GArgs sa{};
  sa.A = qb;  sa.lda = 1024; sa.aBS = (long)SEQ*1024;
  sa.Bm = kb; sa.ldb = 1024; sa.bBS = (long)SEQ*1024;
  sa.C = (void*)sc; sa.ldc = SEQ; sa.cBS = (long)SEQ*SEQ;
  sa.b0 = nullptr; sa.b1 = nullptr; sa.b2 = nullptr;
  sa.K = 1024;
  gemm2<1><<<dim3(16,16,4), 256, 0, stream>>>(sa);

  softmax_causal<<<BS*SEQ, 256, 0, stream>>>(sc, pb);

  // out = P @ V  (B-operand = V^T rows, per-batch column offset; causal K-limit)
  GArgs va{};
  va.A = pb;  va.lda = SEQ;  va.aBS = (long)SEQ*SEQ;
  va.Bm = vt; va.ldb = 8192; va.bBS = SEQ;
  va.C = (void*)out; va.ldc = 1024; va.cBS = (long)SEQ*1024;
  va.b0 = nullptr; va.b1 = nullptr; va.b2 = nullptr;
  va.K = SEQ;
  gemm2<2><<<dim3(16,8,4), 256, 0, stream>>>(va);
}

// Round 3
// 178.247 us; speedup vs baseline: 1.2101x; 1.2026x over previous
//
#include <hip/hip_runtime.h>
#include <cstdint>

#define DEV __device__ __forceinline__

typedef __attribute__((ext_vector_type(4))) float f32x4;
typedef __attribute__((ext_vector_type(8))) short short8;
typedef __attribute__((ext_vector_type(4))) unsigned short u16x4;

constexpr int BS  = 4;
constexpr int SEQ = 2048;

DEV ushort f2b(float f){
  uint32_t u = __builtin_bit_cast(uint32_t, f);
  u += 0x7fffu + ((u >> 16) & 1u);
  return (ushort)(u >> 16);
}
DEV float b2f(ushort h){
  uint32_t u = (uint32_t)h << 16;
  return __builtin_bit_cast(float, u);
}

DEV void gload_lds16(const void* g, void* l){
  __builtin_amdgcn_global_load_lds(
      (const __attribute__((address_space(1))) unsigned int*)g,
      (__attribute__((address_space(3))) unsigned int*)l, 16, 0, 0);
}

#define BAR()    __builtin_amdgcn_s_barrier()
#define PRIO(x)  __builtin_amdgcn_s_setprio(x)
#define SCHEDB() __builtin_amdgcn_sched_barrier(0)
#define LGKM0()  asm volatile("s_waitcnt lgkmcnt(0)" ::: "memory")
#define WAITV4() asm volatile("s_waitcnt vmcnt(4)" ::: "memory")

// ---------- fp32 -> bf16 convert ----------
__global__ __launch_bounds__(256) void convert_f2b8(const float* __restrict__ src,
                                                    ushort* __restrict__ dst){
  long i = (long)blockIdx.x * 256 + threadIdx.x;
  const f32x4* s4 = (const f32x4*)src;
  f32x4 a = s4[i*2], b = s4[i*2+1];
  short8 o;
  o[0]=(short)f2b(a[0]); o[1]=(short)f2b(a[1]); o[2]=(short)f2b(a[2]); o[3]=(short)f2b(a[3]);
  o[4]=(short)f2b(b[0]); o[5]=(short)f2b(b[1]); o[6]=(short)f2b(b[2]); o[7]=(short)f2b(b[3]);
  ((short8*)dst)[i] = o;
}

// ---------- transpose fp32 [R][C] -> bf16 [C][R] ----------
__global__ __launch_bounds__(256) void transpose_f2b(const float* __restrict__ src,
                                                     ushort* __restrict__ dst,
                                                     int R, int C){
  __shared__ float t[32][33];
  int c0 = blockIdx.x * 32, r0 = blockIdx.y * 32;
  int tx = threadIdx.x, ty = threadIdx.y;
  #pragma unroll
  for (int k=0;k<4;k++) t[ty+k*8][tx] = src[(long)(r0+ty+k*8)*C + c0+tx];
  __syncthreads();
  #pragma unroll
  for (int k=0;k<4;k++) dst[(long)(c0+ty+k*8)*R + r0+tx] = f2b(t[tx][ty+k*8]);
}

// ---------- transpose bf16 [R][C] -> bf16 [C][R] ----------
__global__ __launch_bounds__(256) void transpose_b2b(const ushort* __restrict__ src,
                                                     ushort* __restrict__ dst,
                                                     int R, int C){
  __shared__ ushort t[32][33];
  int c0 = blockIdx.x * 32, r0 = blockIdx.y * 32;
  int tx = threadIdx.x, ty = threadIdx.y;
  #pragma unroll
  for (int k=0;k<4;k++) t[ty+k*8][tx] = src[(long)(r0+ty+k*8)*C + c0+tx];
  __syncthreads();
  #pragma unroll
  for (int k=0;k<4;k++) dst[(long)(c0+ty+k*8)*R + r0+tx] = t[tx][ty+k*8];
}

struct GArgs {
  const ushort* A;  long lda; long aBS;
  const ushort* Bm; long ldb; long bBS;
  void* C;          long ldc; long cBS;
  const float* b0; const float* b1; const float* b2;
  int K;
};

// =====================================================================
// gemmA: 256x256 tile, BK=64, 8 waves (2Mx4N), 4-phase/K-tile, 128KiB LDS
// LDS layout per buf (65536B): A-h0 @0, A-h1 @16384, B-h0 @32768, B-h1 @49152
// each half: [kk=2][row=128][32 bf16] (64B rows), swizzle byte^=((byte>>9)&1)<<5
// QKV mode: C = bf16 q/k/v with bias.
// =====================================================================
__global__ __launch_bounds__(512, 2) void gemmA_qkv(GArgs g){
  extern __shared__ char sm[];
  const int tid = threadIdx.x;
  const int wid = tid >> 6, lane = tid & 63;
  const int wr = wid >> 2, wc = wid & 3;
  const int lr = lane & 15, lk = lane >> 4;
  const int f5 = ((lr >> 3) & 1) << 5;

  int fid = blockIdx.x;                       // 384 blocks, 384%8==0
  int swz = (fid & 7) * 48 + (fid >> 3);      // XCD-aware swizzle
  const int m0 = (swz & 31) * 256;
  const int n0 = (swz >> 5) * 256;

  const long lda2 = g.lda * 2, ldb2 = g.ldb * 2;
  const int sr  = tid >> 2;
  const int scb = (lane & 3) << 4;
  const int scbp = scb ^ (((sr >> 3) & 1) << 5);
  const char* ar0 = (const char*)g.A  + (long)(m0 + sr      )*lda2 + scbp;
  const char* ar1 = (const char*)g.A  + (long)(m0 + 128 + sr)*lda2 + scbp;
  const char* br0 = (const char*)g.Bm + (long)(n0 + sr      )*ldb2 + scbp;
  const char* br1 = (const char*)g.Bm + (long)(n0 + 128 + sr)*ldb2 + scbp;
  const int dwo = wid << 10;                  // wave-uniform dest chunk

  auto ST = [&](const char* row, int c, int off, int k0){
    const char* p = row + k0*2;
    char* d = sm + c*65536 + off + dwo;
    gload_lds16(p,      d);
    gload_lds16(p + 64, d + 8192);
  };

  const int aoffs = wr*16384 + lr*64 + ((lk*16) ^ f5);
  const int boffs = 32768 + (wc>>1)*16384 + ((wc&1)*64 + lr)*64 + ((lk*16) ^ f5);

  f32x4 acc[8][4];
  #pragma unroll
  for (int m=0;m<8;m++)
    #pragma unroll
    for (int n=0;n<4;n++) acc[m][n] = f32x4{0.f,0.f,0.f,0.f};

  const int NT = g.K >> 6;                    // K=1024 -> 16
  // prologue: tile0 full + tile1 B
  ST(ar0, 0, 0, 0);     ST(ar1, 0, 16384, 0);
  ST(br0, 0, 32768, 0); ST(br1, 0, 49152, 0);
  ST(br0, 1, 32768, 64); ST(br1, 1, 49152, 64);
  WAITV4(); BAR();

  for (int t = 0; t < NT; ++t){
    const int c = t & 1;
    const char* base = sm + c*65536;
    const int kA = ((t+1) < NT ? (t+1) : NT-1) << 6;
    const int kB = ((t+2) < NT ? (t+2) : NT-1) << 6;
    short8 bf[4][2], af[2][2];
    // ---- phase 0: all B + A(m0,m1); stage A(t+1) ----
    ST(ar0, c^1, 0, kA); ST(ar1, c^1, 16384, kA);
    #pragma unroll
    for (int n=0;n<4;n++)
      #pragma unroll
      for (int kk=0;kk<2;kk++)
        bf[n][kk] = *(const short8*)(base + boffs + kk*8192 + n*1024);
    #pragma unroll
    for (int mm=0;mm<2;mm++)
      #pragma unroll
      for (int kk=0;kk<2;kk++)
        af[mm][kk] = *(const short8*)(base + aoffs + kk*8192 + mm*1024);
    LGKM0(); SCHEDB();
    PRIO(1);
    #pragma unroll
    for (int kk=0;kk<2;kk++)
      #pragma unroll
      for (int mm=0;mm<2;mm++)
        #pragma unroll
        for (int n=0;n<4;n++)
          acc[mm][n] = __builtin_amdgcn_mfma_f32_16x16x32_bf16(af[mm][kk], bf[n][kk], acc[mm][n], 0,0,0);
    PRIO(0);
    BAR();
    // ---- phases 1..3: A(m2..m7); stage B(t+2) halves at p1,p2 ----
    #pragma unroll
    for (int p=1;p<4;p++){
      if (p == 1) ST(br0, c, 32768, kB);
      if (p == 2) ST(br1, c, 49152, kB);
      #pragma unroll
      for (int mm=0;mm<2;mm++)
        #pragma unroll
        for (int kk=0;kk<2;kk++)
          af[mm][kk] = *(const short8*)(base + aoffs + kk*8192 + (p*2+mm)*1024);
      LGKM0(); SCHEDB();
      PRIO(1);
      #pragma unroll
      for (int kk=0;kk<2;kk++)
        #pragma unroll
        for (int mm=0;mm<2;mm++)
          #pragma unroll
          for (int n=0;n<4;n++)
            acc[p*2+mm][n] = __builtin_amdgcn_mfma_f32_16x16x32_bf16(af[mm][kk], bf[n][kk], acc[p*2+mm][n], 0,0,0);
      PRIO(0);
      if (p == 3) WAITV4();
      BAR();
    }
  }

  // epilogue: bf16 + bias, route to q/k/v
  int sel = n0 >> 10;
  const float* bp = (sel == 0) ? g.b0 : (sel == 1) ? g.b1 : g.b2;
  ushort* Cq = (ushort*)g.C + (long)sel * 8388608;
  #pragma unroll
  for (int m=0;m<8;m++){
    int row0 = m0 + wr*128 + m*16 + lk*4;
    #pragma unroll
    for (int n=0;n<4;n++){
      int col  = n0 + wc*64 + n*16 + lr;
      int colq = col & 1023;
      float bv = bp[colq];
      #pragma unroll
      for (int i=0;i<4;i++)
        Cq[(long)(row0+i)*1024 + colq] = f2b(acc[m][n][i] + bv);
    }
  }
}

// =====================================================================
// gemmB: 128x256 tile, BK=64, 8 waves (2Mx4N), 2-phase/K-tile, 96KiB LDS
// LDS per buf (49152B): A @0 (16KB), B-h0 @16384, B-h1 @32768
// MODE 1: scores (bf16 out, skip tiles n0 > m0+127)
// MODE 2: PV (fp32 out, Keff = m0+128)
// =====================================================================
template<int MODE>
__global__ __launch_bounds__(512, 2) void gemmB(GArgs g){
  extern __shared__ char sm[];
  const int m0 = blockIdx.x * 128, n0 = blockIdx.y * 256;
  const int z  = blockIdx.z;
  if (MODE == 1 && n0 > m0 + 127) return;
  const int tid = threadIdx.x;
  const int wid = tid >> 6, lane = tid & 63;
  const int wr = wid >> 2, wc = wid & 3;
  const int lr = lane & 15, lk = lane >> 4;
  const int f5 = ((lr >> 3) & 1) << 5;

  const char* Ab = (const char*)(g.A  + (long)z * g.aBS);
  const char* Bb = (const char*)(g.Bm + (long)z * g.bBS);
  const long lda2 = g.lda * 2, ldb2 = g.ldb * 2;
  const int sr  = tid >> 2;
  const int scb = (lane & 3) << 4;
  const int scbp = scb ^ (((sr >> 3) & 1) << 5);
  const char* ar0 = Ab + (long)(m0 + sr)*lda2 + scbp;
  const char* br0 = Bb + (long)(n0 + sr      )*ldb2 + scbp;
  const char* br1 = Bb + (long)(n0 + 128 + sr)*ldb2 + scbp;
  const int dwo = wid << 10;

  auto ST = [&](const char* row, int c, int off, int k0){
    const char* p = row + k0*2;
    char* d = sm + c*49152 + off + dwo;
    gload_lds16(p,      d);
    gload_lds16(p + 64, d + 8192);
  };

  const int aoffs = (wr*64 + lr)*64 + ((lk*16) ^ f5);
  const int boffs = 16384 + (wc>>1)*16384 + ((wc&1)*64 + lr)*64 + ((lk*16) ^ f5);

  f32x4 acc[4][4];
  #pragma unroll
  for (int m=0;m<4;m++)
    #pragma unroll
    for (int n=0;n<4;n++) acc[m][n] = f32x4{0.f,0.f,0.f,0.f};

  const int Keff = (MODE == 2) ? (m0 + 128) : g.K;
  const int NT = Keff >> 6;                  // >= 2 always
  ST(ar0, 0, 0, 0);
  ST(br0, 0, 16384, 0); ST(br1, 0, 32768, 0);
  ST(br0, 1, 16384, 64); ST(br1, 1, 32768, 64);
  WAITV4(); BAR();

  for (int t = 0; t < NT; ++t){
    const int c = t & 1;
    const char* base = sm + c*49152;
    const int kA = ((t+1) < NT ? (t+1) : NT-1) << 6;
    const int kB = ((t+2) < NT ? (t+2) : NT-1) << 6;
    short8 bf[4][2], af[2][2];
    // ---- phase 0: all B + A(m0,m1); stage A(t+1) ----
    ST(ar0, c^1, 0, kA);
    #pragma unroll
    for (int n=0;n<4;n++)
      #pragma unroll
      for (int kk=0;kk<2;kk++)
        bf[n][kk] = *(const short8*)(base + boffs + kk*8192 + n*1024);
    #pragma unroll
    for (int mm=0;mm<2;mm++)
      #pragma unroll
      for (int kk=0;kk<2;kk++)
        af[mm][kk] = *(const short8*)(base + aoffs + kk*8192 + mm*1024);
    LGKM0(); SCHEDB();
    PRIO(1);
    #pragma unroll
    for (int kk=0;kk<2;kk++)
      #pragma unroll
      for (int mm=0;mm<2;mm++)
        #pragma unroll
        for (int n=0;n<4;n++)
          acc[mm][n] = __builtin_amdgcn_mfma_f32_16x16x32_bf16(af[mm][kk], bf[n][kk], acc[mm][n], 0,0,0);
    PRIO(0);
    BAR();
    // ---- phase 1: A(m2,m3); stage B(t+2) both halves ----
    ST(br0, c, 16384, kB); ST(br1, c, 32768, kB);
    #pragma unroll
    for (int mm=0;mm<2;mm++)
      #pragma unroll
      for (int kk=0;kk<2;kk++)
        af[mm][kk] = *(const short8*)(base + aoffs + kk*8192 + (2+mm)*1024);
    LGKM0(); SCHEDB();
    PRIO(1);
    #pragma unroll
    for (int kk=0;kk<2;kk++)
      #pragma unroll
      for (int mm=0;mm<2;mm++)
        #pragma unroll
        for (int n=0;n<4;n++)
          acc[2+mm][n] = __builtin_amdgcn_mfma_f32_16x16x32_bf16(af[mm][kk], bf[n][kk], acc[2+mm][n], 0,0,0);
    PRIO(0);
    WAITV4();
    BAR();
  }

  long cz = (long)z * g.cBS;
  #pragma unroll
  for (int m=0;m<4;m++){
    int row0 = m0 + wr*64 + m*16 + lk*4;
    #pragma unroll
    for (int n=0;n<4;n++){
      int col = n0 + wc*64 + n*16 + lr;
      #pragma unroll
      for (int i=0;i<4;i++){
        long off = cz + (long)(row0+i)*g.ldc + col;
        if (MODE == 1) ((ushort*)g.C)[off] = f2b(acc[m][n][i]);
        else           ((float*)g.C)[off]  = acc[m][n][i];
      }
    }
  }
}

// ---------- causal row softmax on bf16 scores -> bf16 P ----------
__global__ __launch_bounds__(256) void softmax_causal_b(const ushort* __restrict__ sc,
                                                        ushort* __restrict__ P){
  int row = blockIdx.x & (SEQ-1);
  int b   = blockIdx.x >> 11;
  const short8* srow = (const short8*)(sc + ((long)b*SEQ + row)*(long)SEQ);
  ushort* prow = P + ((long)b*SEQ + row)*(long)SEQ;
  int tid = threadIdx.x;
  int lane = tid & 63, wid = tid >> 6;
  const float scale = 0.03125f;
  float x[8]; float mx = -INFINITY;
  int base = tid * 8;
  if (base <= row){
    short8 v = srow[tid];
    #pragma unroll
    for (int j=0;j<8;j++){
      float t = (base + j <= row) ? b2f((ushort)v[j]) : -INFINITY;
      x[j] = t; mx = fmaxf(mx, t);
    }
  } else {
    #pragma unroll
    for (int j=0;j<8;j++) x[j] = -INFINITY;
  }
  #pragma unroll
  for (int off=1; off<64; off<<=1) mx = fmaxf(mx, __shfl_xor(mx, off));
  __shared__ float rb[8];
  if (lane == 0) rb[wid] = mx;
  __syncthreads();
  mx = fmaxf(fmaxf(rb[0],rb[1]), fmaxf(rb[2],rb[3]));
  float sum = 0.f; float e[8];
  #pragma unroll
  for (int i=0;i<8;i++){ e[i] = __expf((x[i]-mx)*scale); sum += e[i]; }
  #pragma unroll
  for (int off=1; off<64; off<<=1) sum += __shfl_xor(sum, off);
  if (lane == 0) rb[4+wid] = sum;
  __syncthreads();
  sum = (rb[4]+rb[5]) + (rb[6]+rb[7]);
  float inv = 1.0f / sum;
  int wlim = row | 127;                       // PV (BM=128) reads cols <= m0+127
  if (base <= wlim){
    short8 o;
    #pragma unroll
    for (int j=0;j<8;j++) o[j] = (short)f2b(e[j]*inv);
    ((short8*)prow)[tid] = o;
  }
}

extern "C" void kernel_launch(void* const* d_in, const int* in_sizes, int n_in,
                              void* d_out, int out_size, void* d_ws, size_t ws_size,
                              hipStream_t stream){
  const float* x  = (const float*)d_in[0];
  const float* Wq = (const float*)d_in[1];
  const float* Wk = (const float*)d_in[2];
  const float* Wv = (const float*)d_in[3];
  const float* bq = (const float*)d_in[4];
  const float* bk = (const float*)d_in[5];
  const float* bv = (const float*)d_in[6];
  float* out = (float*)d_out;

  // workspace layout (bytes)
  const long XB = 0;            // x bf16 [8192][1024]          16 MB
  const long WT = 16777216;     // Wt bf16 x3 [1024][1024]       6 MB
  const long QB = 23068672;     // q/k/v bf16 contiguous        48 MB
  const long VT = 73400320;     // v^T bf16 [1024][8192]        16 MB
  const long SC = 90177536;     // scores bf16 [4][2048][2048]  32 MB
  const long NEED = 157286400;
  const long PB = 0;            // P bf16 overlays dead xb/wt/q-front
  if ((long)ws_size < NEED) return;

  char* ws = (char*)d_ws;
  ushort* xb = (ushort*)(ws + XB);
  ushort* wt = (ushort*)(ws + WT);
  ushort* qb = (ushort*)(ws + QB);
  ushort* kb = qb + 8388608;
  ushort* vb = qb + 16777216;
  ushort* vt = (ushort*)(ws + VT);
  ushort* sc = (ushort*)(ws + SC);
  ushort* pb = (ushort*)(ws + PB);

  // allow >64KB dynamic LDS (idempotent, capture-transparent)
  hipFuncSetAttribute(reinterpret_cast<const void*>(&gemmA_qkv),
                      hipFuncAttributeMaxDynamicSharedMemorySize, 131072);
  hipFuncSetAttribute(reinterpret_cast<const void*>(&gemmB<1>),
                      hipFuncAttributeMaxDynamicSharedMemorySize, 98304);
  hipFuncSetAttribute(reinterpret_cast<const void*>(&gemmB<2>),
                      hipFuncAttributeMaxDynamicSharedMemorySize, 98304);

  dim3 tb(32, 8);

  convert_f2b8<<<4096, 256, 0, stream>>>(x, xb);
  transpose_f2b<<<dim3(32,32), tb, 0, stream>>>(Wq, wt + 0,       1024, 1024);
  transpose_f2b<<<dim3(32,32), tb, 0, stream>>>(Wk, wt + 1048576, 1024, 1024);
  transpose_f2b<<<dim3(32,32), tb, 0, stream>>>(Wv, wt + 2097152, 1024, 1024);

  // fused projections: [q|k|v] = x @ [Wq|Wk|Wv] + bias, M=8192 N=3072 K=1024
  GArgs pa{};
  pa.A = xb; pa.lda = 1024; pa.aBS = 0;
  pa.Bm = wt; pa.ldb = 1024; pa.bBS = 0;
  pa.C = (void*)qb; pa.ldc = 1024; pa.cBS = 0;
  pa.b0 = bq; pa.b1 = bk; pa.b2 = bv;
  pa.K = 1024;
  gemmA_qkv<<<384, 512, 131072, stream>>>(pa);

  transpose_b2b<<<dim3(32,256), tb, 0, stream>>>(vb, vt, 8192, 1024);

  // scores = q @ k^T per batch, bf16 out, causal tile skip
  GArgs sa{};
  sa.A = qb;  sa.lda = 1024; sa.aBS = (long)SEQ*1024;
  sa.Bm = kb; sa.ldb = 1024; sa.bBS = (long)SEQ*1024;
  sa.C = (void*)sc; sa.ldc = SEQ; sa.cBS = (long)SEQ*SEQ;
  sa.b0 = nullptr; sa.b1 = nullptr; sa.b2 = nullptr;
  sa.K = 1024;
  gemmB<1><<<dim3(16,8,4), 512, 98304, stream>>>(sa);

  softmax_causal_b<<<BS*SEQ, 256, 0, stream>>>(sc, pb);

  // out = P @ V  (B = V^T rows, per-batch column offset; Keff = m0+128)
  GArgs va{};
  va.A = pb;  va.lda = SEQ;  va.aBS = (long)SEQ*SEQ;
  va.Bm = vt; va.ldb = 8192; va.bBS = SEQ;
  va.C = (void*)out; va.ldc = 1024; va.cBS = (long)SEQ*1024;
  va.b0 = nullptr; va.b1 = nullptr; va.b2 = nullptr;
  va.K = SEQ;
  gemmB<2><<<dim3(16,4,4), 512, 98304, stream>>>(va);
}

// Round 4
// 173.837 us; speedup vs baseline: 1.2408x; 1.0254x over previous
//
#include <hip/hip_runtime.h>
#include <cstdint>

#define DEV __device__ __forceinline__

typedef __attribute__((ext_vector_type(4))) float f32x4;
typedef __attribute__((ext_vector_type(8))) short short8;
typedef __attribute__((ext_vector_type(4))) unsigned short u16x4;

constexpr int BS  = 4;
constexpr int SEQ = 2048;

DEV ushort f2b(float f){
  uint32_t u = __builtin_bit_cast(uint32_t, f);
  u += 0x7fffu + ((u >> 16) & 1u);
  return (ushort)(u >> 16);
}
DEV float b2f(ushort h){
  uint32_t u = (uint32_t)h << 16;
  return __builtin_bit_cast(float, u);
}

DEV void gload_lds16(const void* g, void* l){
  __builtin_amdgcn_global_load_lds(
      (const __attribute__((address_space(1))) unsigned int*)g,
      (__attribute__((address_space(3))) unsigned int*)l, 16, 0, 0);
}

#define BAR()    __builtin_amdgcn_s_barrier()
#define PRIO(x)  __builtin_amdgcn_s_setprio(x)
#define SCHEDB() __builtin_amdgcn_sched_barrier(0)
#define LGKM0()  asm volatile("s_waitcnt lgkmcnt(0)" ::: "memory")
#define WAITV(n) asm volatile("s_waitcnt vmcnt(" #n ")" ::: "memory")

// ---------- fp32 -> bf16 convert ----------
__global__ __launch_bounds__(256) void convert_f2b8(const float* __restrict__ src,
                                                    ushort* __restrict__ dst){
  long i = (long)blockIdx.x * 256 + threadIdx.x;
  const f32x4* s4 = (const f32x4*)src;
  f32x4 a = s4[i*2], b = s4[i*2+1];
  short8 o;
  o[0]=(short)f2b(a[0]); o[1]=(short)f2b(a[1]); o[2]=(short)f2b(a[2]); o[3]=(short)f2b(a[3]);
  o[4]=(short)f2b(b[0]); o[5]=(short)f2b(b[1]); o[6]=(short)f2b(b[2]); o[7]=(short)f2b(b[3]);
  ((short8*)dst)[i] = o;
}

// ---------- transpose fp32 [R][C] -> bf16 [C][R] ----------
__global__ __launch_bounds__(256) void transpose_f2b(const float* __restrict__ src,
                                                     ushort* __restrict__ dst,
                                                     int R, int C){
  __shared__ float t[32][33];
  int c0 = blockIdx.x * 32, r0 = blockIdx.y * 32;
  int tx = threadIdx.x, ty = threadIdx.y;
  #pragma unroll
  for (int k=0;k<4;k++) t[ty+k*8][tx] = src[(long)(r0+ty+k*8)*C + c0+tx];
  __syncthreads();
  #pragma unroll
  for (int k=0;k<4;k++) dst[(long)(c0+ty+k*8)*R + r0+tx] = f2b(t[tx][ty+k*8]);
}

// ---------- transpose bf16 [R][C] -> bf16 [C][R] ----------
__global__ __launch_bounds__(256) void transpose_b2b(const ushort* __restrict__ src,
                                                     ushort* __restrict__ dst,
                                                     int R, int C){
  __shared__ ushort t[32][33];
  int c0 = blockIdx.x * 32, r0 = blockIdx.y * 32;
  int tx = threadIdx.x, ty = threadIdx.y;
  #pragma unroll
  for (int k=0;k<4;k++) t[ty+k*8][tx] = src[(long)(r0+ty+k*8)*C + c0+tx];
  __syncthreads();
  #pragma unroll
  for (int k=0;k<4;k++) dst[(long)(c0+ty+k*8)*R + r0+tx] = t[tx][ty+k*8];
}

struct GArgs {
  const ushort* A;  long lda; long aBS;
  const ushort* Bm; long ldb; long bBS;
  void* C;          long ldc; long cBS;
  const float* b0; const float* b1; const float* b2;
  int K;
};

// =====================================================================
// gemmA_qkv: 256x192 tile, BK=64, 8 waves (2Mx4N), 4-phase/K-tile.
// LDS per buf (57344B): A 32KB @0 (4 units), B 24KB @32768 (3 units).
// Unit = 64 rows as [kk=2][64r][64B], swizzle: chunk-byte ^ ((row>>3&1)<<5),
// applied on pre-swizzled global source + on ds_read addr (both-sides).
// Grid 512 = 32m x 16n = exactly 2 rounds; XCD x owns m-tiles [4x,4x+4)
// so each XCD's A working set = 2MB (L2-resident).
// =====================================================================
__global__ __launch_bounds__(512, 2) void gemmA_qkv(GArgs g){
  extern __shared__ char sm[];
  const int tid = threadIdx.x;
  const int wid = tid >> 6, lane = tid & 63;
  const int wr = wid >> 2, wc = wid & 3;
  const int lr = lane & 15, lk = lane >> 4;
  const int f5 = ((lr >> 3) & 1) << 5;

  const int fid = blockIdx.x;                 // 512 blocks
  const int xcd = fid & 7, j = fid >> 3;      // j in [0,64)
  const int m0 = (xcd * 4 + (j & 3)) * 256;
  const int n0 = (j >> 2) * 192;

  const long lda2 = g.lda * 2, ldb2 = g.ldb * 2;
  // staging geometry: thread -> (k-half, row-in-unit, 16B chunk); dest = tid*16
  const int skk = tid >> 8;
  const int srr = (tid >> 2) & 63;
  const int scc = tid & 3;
  const int scb = (scc * 16) ^ (((srr >> 3) & 1) << 5);   // pre-swizzled source col
  const char* aU0 = (const char*)g.A  + (long)(m0       + srr)*lda2 + skk*64 + scb;
  const char* aU1 = (const char*)g.A  + (long)(m0 +  64 + srr)*lda2 + skk*64 + scb;
  const char* aU2 = (const char*)g.A  + (long)(m0 + 128 + srr)*lda2 + skk*64 + scb;
  const char* aU3 = (const char*)g.A  + (long)(m0 + 192 + srr)*lda2 + skk*64 + scb;
  const char* bU0 = (const char*)g.Bm + (long)(n0       + srr)*ldb2 + skk*64 + scb;
  const char* bU1 = (const char*)g.Bm + (long)(n0 +  64 + srr)*ldb2 + skk*64 + scb;
  const char* bU2 = (const char*)g.Bm + (long)(n0 + 128 + srr)*ldb2 + skk*64 + scb;
  const int dst = tid * 16;

#define STA(u, cb, k0) gload_lds16(aU##u + (k0)*2, sm + (cb)*57344 + u*8192 + dst)
#define STB(u, cb, k0) gload_lds16(bU##u + (k0)*2, sm + (cb)*57344 + 32768 + u*8192 + dst)

  // ds_read offsets (compile-time-unrolled indices only)
  int aoff[8], boff[3];
  #pragma unroll
  for (int mm=0;mm<8;mm++)
    aoff[mm] = wr*16384 + (mm>>2)*8192 + (mm&3)*1024 + lr*64 + ((lk*16) ^ f5);
  #pragma unroll
  for (int nn=0;nn<3;nn++){
    int br = wc*48 + nn*16 + lr;
    boff[nn] = 32768 + (br>>6)*8192 + (br&63)*64 + ((lk*16) ^ f5);
  }

  f32x4 acc[8][3];
  #pragma unroll
  for (int m=0;m<8;m++)
    #pragma unroll
    for (int n=0;n<3;n++) acc[m][n] = f32x4{0.f,0.f,0.f,0.f};

  const int NT = g.K >> 6;                    // 16
  // prologue: A(0),B(0) -> buf0; B(1) -> buf1
  STA(0,0,0); STA(1,0,0); STA(2,0,0); STA(3,0,0);
  STB(0,0,0); STB(1,0,0); STB(2,0,0);
  STB(0,1,64); STB(1,1,64); STB(2,1,64);
  WAITV(3); BAR();

  short8 bf[3][2], af[2][2];
#define READ_AF(MB) \
    af[0][0] = *(const short8*)(base + aoff[MB  ]);        \
    af[0][1] = *(const short8*)(base + aoff[MB  ] + 4096); \
    af[1][0] = *(const short8*)(base + aoff[MB+1]);        \
    af[1][1] = *(const short8*)(base + aoff[MB+1] + 4096);
#define MFMA6(MB) \
    PRIO(1); \
    _Pragma("unroll") \
    for (int kk=0;kk<2;kk++) \
      _Pragma("unroll") \
      for (int mm=0;mm<2;mm++) \
        _Pragma("unroll") \
        for (int nn=0;nn<3;nn++) \
          acc[MB+mm][nn] = __builtin_amdgcn_mfma_f32_16x16x32_bf16(af[mm][kk], bf[nn][kk], acc[MB+mm][nn], 0,0,0); \
    PRIO(0);

  for (int t = 0; t < NT; ++t){
    const int c = t & 1;
    const char* base = sm + c*57344;
    const int kA = ((t+1) < NT ? (t+1) : NT-1) << 6;
    const int kB = ((t+2) < NT ? (t+2) : NT-1) << 6;
    // ---- phase 0: stage A(t+1) u0,u1; read all B frags + A m0,m1 ----
    STA(0, c^1, kA); STA(1, c^1, kA);
    #pragma unroll
    for (int nn=0;nn<3;nn++){
      bf[nn][0] = *(const short8*)(base + boff[nn]);
      bf[nn][1] = *(const short8*)(base + boff[nn] + 4096);
    }
    READ_AF(0);
    LGKM0(); SCHEDB();
    MFMA6(0);
    BAR();
    // ---- phase 1: stage A(t+1) u2,u3; A m2,m3 ----
    STA(2, c^1, kA); STA(3, c^1, kA);
    READ_AF(2);
    LGKM0(); SCHEDB();
    MFMA6(2);
    BAR();
    // ---- phase 2: stage B(t+2) u0,u1; A m4,m5 ----
    STB(0, c, kB); STB(1, c, kB);
    READ_AF(4);
    LGKM0(); SCHEDB();
    MFMA6(4);
    BAR();
    // ---- phase 3: stage B(t+2) u2; A m6,m7; counted drain ----
    STB(2, c, kB);
    READ_AF(6);
    LGKM0(); SCHEDB();
    MFMA6(6);
    WAITV(3);
    BAR();
  }
  WAITV(0);
#undef STA
#undef STB
#undef READ_AF
#undef MFMA6

  // epilogue: bf16 + bias, per-fragment q/k/v routing (192-tile may straddle)
  #pragma unroll
  for (int nn=0;nn<3;nn++){
    int col  = n0 + wc*48 + nn*16 + lr;
    int sel  = col >> 10;
    int colq = col & 1023;
    const float* bp = (sel == 0) ? g.b0 : (sel == 1) ? g.b1 : g.b2;
    float bv = bp[colq];
    ushort* Cq = (ushort*)g.C + (long)sel * 8388608;
    #pragma unroll
    for (int mm=0;mm<8;mm++){
      int row0 = m0 + wr*128 + mm*16 + lk*4;
      #pragma unroll
      for (int i=0;i<4;i++)
        Cq[(long)(row0+i)*1024 + colq] = f2b(acc[mm][nn][i] + bv);
    }
  }
}

// =====================================================================
// gemmB: 128x256 tile, BK=64, 8 waves (2Mx4N), 2-phase/K-tile, 96KiB LDS
// MODE 1: scores (bf16 out, skip tiles n0 > m0+127)
// MODE 2: PV (fp32 out, Keff = m0+128)
// =====================================================================
template<int MODE>
__global__ __launch_bounds__(512, 2) void gemmB(GArgs g){
  extern __shared__ char sm[];
  const int m0 = blockIdx.x * 128, n0 = blockIdx.y * 256;
  const int z  = blockIdx.z;
  if (MODE == 1 && n0 > m0 + 127) return;
  const int tid = threadIdx.x;
  const int wid = tid >> 6, lane = tid & 63;
  const int wr = wid >> 2, wc = wid & 3;
  const int lr = lane & 15, lk = lane >> 4;
  const int f5 = ((lr >> 3) & 1) << 5;

  const char* Ab = (const char*)(g.A  + (long)z * g.aBS);
  const char* Bb = (const char*)(g.Bm + (long)z * g.bBS);
  const long lda2 = g.lda * 2, ldb2 = g.ldb * 2;
  const int sr  = tid >> 2;
  const int scb = ((lane & 3) << 4) ^ (((sr >> 3) & 1) << 5);
  const char* ar0 = Ab + (long)(m0 + sr)*lda2 + scb;
  const char* br0 = Bb + (long)(n0 + sr      )*ldb2 + scb;
  const char* br1 = Bb + (long)(n0 + 128 + sr)*ldb2 + scb;
  const int dwo = wid << 10;

  auto ST = [&](const char* row, int c, int off, int k0){
    const char* p = row + k0*2;
    char* d = sm + c*49152 + off + dwo;
    gload_lds16(p,      d);
    gload_lds16(p + 64, d + 8192);
  };

  const int aoffs = (wr*64 + lr)*64 + ((lk*16) ^ f5);
  const int boffs = 16384 + (wc>>1)*16384 + ((wc&1)*64 + lr)*64 + ((lk*16) ^ f5);

  f32x4 acc[4][4];
  #pragma unroll
  for (int m=0;m<4;m++)
    #pragma unroll
    for (int n=0;n<4;n++) acc[m][n] = f32x4{0.f,0.f,0.f,0.f};

  const int Keff = (MODE == 2) ? (m0 + 128) : g.K;
  const int NT = Keff >> 6;
  ST(ar0, 0, 0, 0);
  ST(br0, 0, 16384, 0); ST(br1, 0, 32768, 0);
  ST(br0, 1, 16384, 64); ST(br1, 1, 32768, 64);
  WAITV(4); BAR();

  for (int t = 0; t < NT; ++t){
    const int c = t & 1;
    const char* base = sm + c*49152;
    const int kA = ((t+1) < NT ? (t+1) : NT-1) << 6;
    const int kB = ((t+2) < NT ? (t+2) : NT-1) << 6;
    short8 bf[4][2], af[2][2];
    ST(ar0, c^1, 0, kA);
    #pragma unroll
    for (int n=0;n<4;n++)
      #pragma unroll
      for (int kk=0;kk<2;kk++)
        bf[n][kk] = *(const short8*)(base + boffs + kk*8192 + n*1024);
    #pragma unroll
    for (int mm=0;mm<2;mm++)
      #pragma unroll
      for (int kk=0;kk<2;kk++)
        af[mm][kk] = *(const short8*)(base + aoffs + kk*8192 + mm*1024);
    LGKM0(); SCHEDB();
    PRIO(1);
    #pragma unroll
    for (int kk=0;kk<2;kk++)
      #pragma unroll
      for (int mm=0;mm<2;mm++)
        #pragma unroll
        for (int n=0;n<4;n++)
          acc[mm][n] = __builtin_amdgcn_mfma_f32_16x16x32_bf16(af[mm][kk], bf[n][kk], acc[mm][n], 0,0,0);
    PRIO(0);
    BAR();
    ST(br0, c, 16384, kB); ST(br1, c, 32768, kB);
    #pragma unroll
    for (int mm=0;mm<2;mm++)
      #pragma unroll
      for (int kk=0;kk<2;kk++)
        af[mm][kk] = *(const short8*)(base + aoffs + kk*8192 + (2+mm)*1024);
    LGKM0(); SCHEDB();
    PRIO(1);
    #pragma unroll
    for (int kk=0;kk<2;kk++)
      #pragma unroll
      for (int mm=0;mm<2;mm++)
        #pragma unroll
        for (int n=0;n<4;n++)
          acc[2+mm][n] = __builtin_amdgcn_mfma_f32_16x16x32_bf16(af[mm][kk], bf[n][kk], acc[2+mm][n], 0,0,0);
    PRIO(0);
    WAITV(4);
    BAR();
  }
  WAITV(0);

  long cz = (long)z * g.cBS;
  #pragma unroll
  for (int m=0;m<4;m++){
    int row0 = m0 + wr*64 + m*16 + lk*4;
    #pragma unroll
    for (int n=0;n<4;n++){
      int col = n0 + wc*64 + n*16 + lr;
      #pragma unroll
      for (int i=0;i<4;i++){
        long off = cz + (long)(row0+i)*g.ldc + col;
        if (MODE == 1) ((ushort*)g.C)[off] = f2b(acc[m][n][i]);
        else           ((float*)g.C)[off]  = acc[m][n][i];
      }
    }
  }
}

// ---------- causal row softmax on bf16 scores -> bf16 P ----------
__global__ __launch_bounds__(256) void softmax_causal_b(const ushort* __restrict__ sc,
                                                        ushort* __restrict__ P){
  int row = blockIdx.x & (SEQ-1);
  int b   = blockIdx.x >> 11;
  const short8* srow = (const short8*)(sc + ((long)b*SEQ + row)*(long)SEQ);
  ushort* prow = P + ((long)b*SEQ + row)*(long)SEQ;
  int tid = threadIdx.x;
  int lane = tid & 63, wid = tid >> 6;
  const float scale = 0.03125f;
  float x[8]; float mx = -INFINITY;
  int base = tid * 8;
  if (base <= row){
    short8 v = srow[tid];
    #pragma unroll
    for (int j=0;j<8;j++){
      float t = (base + j <= row) ? b2f((ushort)v[j]) : -INFINITY;
      x[j] = t; mx = fmaxf(mx, t);
    }
  } else {
    #pragma unroll
    for (int j=0;j<8;j++) x[j] = -INFINITY;
  }
  #pragma unroll
  for (int off=1; off<64; off<<=1) mx = fmaxf(mx, __shfl_xor(mx, off));
  __shared__ float rb[8];
  if (lane == 0) rb[wid] = mx;
  __syncthreads();
  mx = fmaxf(fmaxf(rb[0],rb[1]), fmaxf(rb[2],rb[3]));
  float sum = 0.f; float e[8];
  #pragma unroll
  for (int i=0;i<8;i++){ e[i] = __expf((x[i]-mx)*scale); sum += e[i]; }
  #pragma unroll
  for (int off=1; off<64; off<<=1) sum += __shfl_xor(sum, off);
  if (lane == 0) rb[4+wid] = sum;
  __syncthreads();
  sum = (rb[4]+rb[5]) + (rb[6]+rb[7]);
  float inv = 1.0f / sum;
  int wlim = row | 127;
  if (base <= wlim){
    short8 o;
    #pragma unroll
    for (int j=0;j<8;j++) o[j] = (short)f2b(e[j]*inv);
    ((short8*)prow)[tid] = o;
  }
}

extern "C" void kernel_launch(void* const* d_in, const int* in_sizes, int n_in,
                              void* d_out, int out_size, void* d_ws, size_t ws_size,
                              hipStream_t stream){
  const float* x  = (const float*)d_in[0];
  const float* Wq = (const float*)d_in[1];
  const float* Wk = (const float*)d_in[2];
  const float* Wv = (const float*)d_in[3];
  const float* bq = (const float*)d_in[4];
  const float* bk = (const float*)d_in[5];
  const float* bv = (const float*)d_in[6];
  float* out = (float*)d_out;

  const long XB = 0;            // x bf16 [8192][1024]          16 MB
  const long WT = 16777216;     // Wt bf16 x3 [1024][1024]       6 MB
  const long QB = 23068672;     // q/k/v bf16 contiguous        48 MB
  const long VT = 73400320;     // v^T bf16 [1024][8192]        16 MB
  const long SC = 90177536;     // scores bf16 [4][2048][2048]  32 MB
  const long NEED = 157286400;
  const long PB = 0;            // P bf16 overlays dead xb/wt/q-front
  if ((long)ws_size < NEED) return;

  char* ws = (char*)d_ws;
  ushort* xb = (ushort*)(ws + XB);
  ushort* wt = (ushort*)(ws + WT);
  ushort* qb = (ushort*)(ws + QB);
  ushort* kb = qb + 8388608;
  ushort* vb = qb + 16777216;
  ushort* vt = (ushort*)(ws + VT);
  ushort* sc = (ushort*)(ws + SC);
  ushort* pb = (ushort*)(ws + PB);

  hipFuncSetAttribute(reinterpret_cast<const void*>(&gemmA_qkv),
                      hipFuncAttributeMaxDynamicSharedMemorySize, 114688);
  hipFuncSetAttribute(reinterpret_cast<const void*>(&gemmB<1>),
                      hipFuncAttributeMaxDynamicSharedMemorySize, 98304);
  hipFuncSetAttribute(reinterpret_cast<const void*>(&gemmB<2>),
                      hipFuncAttributeMaxDynamicSharedMemorySize, 98304);

  dim3 tb(32, 8);

  convert_f2b8<<<4096, 256, 0, stream>>>(x, xb);
  transpose_f2b<<<dim3(32,32), tb, 0, stream>>>(Wq, wt + 0,       1024, 1024);
  transpose_f2b<<<dim3(32,32), tb, 0, stream>>>(Wk, wt + 1048576, 1024, 1024);
  transpose_f2b<<<dim3(32,32), tb, 0, stream>>>(Wv, wt + 2097152, 1024, 1024);

  // fused projections: [q|k|v] = x @ [Wq|Wk|Wv] + bias, M=8192 N=3072 K=1024
  GArgs pa{};
  pa.A = xb; pa.lda = 1024; pa.aBS = 0;
  pa.Bm = wt; pa.ldb = 1024; pa.bBS = 0;
  pa.C = (void*)qb; pa.ldc = 1024; pa.cBS = 0;
  pa.b0 = bq; pa.b1 = bk; pa.b2 = bv;
  pa.K = 1024;
  gemmA_qkv<<<512, 512, 114688, stream>>>(pa);

  transpose_b2b<<<dim3(32,256), tb, 0, stream>>>(vb, vt, 8192, 1024);

  // scores = q @ k^T per batch, bf16 out, causal tile skip
  GArgs sa{};
  sa.A = qb;  sa.lda = 1024; sa.aBS = (long)SEQ*1024;
  sa.Bm = kb; sa.ldb = 1024; sa.bBS = (long)SEQ*1024;
  sa.C = (void*)sc; sa.ldc = SEQ; sa.cBS = (long)SEQ*SEQ;
  sa.b0 = nullptr; sa.b1 = nullptr; sa.b2 = nullptr;
  sa.K = 1024;
  gemmB<1><<<dim3(16,8,4), 512, 98304, stream>>>(sa);

  softmax_causal_b<<<BS*SEQ, 256, 0, stream>>>(sc, pb);

  // out = P @ V  (B = V^T rows, per-batch column offset; Keff = m0+128)
  GArgs va{};
  va.A = pb;  va.lda = SEQ;  va.aBS = (long)SEQ*SEQ;
  va.Bm = vt; va.ldb = 8192; va.bBS = SEQ;
  va.C = (void*)out; va.ldc = 1024; va.cBS = (long)SEQ*1024;
  va.b0 = nullptr; va.b1 = nullptr; va.b2 = nullptr;
  va.K = SEQ;
  gemmB<2><<<dim3(16,4,4), 512, 98304, stream>>>(va);
}